// Round 1
// baseline (423.039 us; speedup 1.0000x reference)
//
#include <hip/hip_runtime.h>
#include <float.h>
#include <math.h>

#define B_ 4
#define L_ 4096
#define H_ 8
#define D_ 64
#define S_ 45      // sample_k == u == 45
#define KC_ 16     // k-chunks for attention pass
#define KCH_ 256   // k per chunk
#define SCALE 0.125f

// ---------------- K1: M[b,h,l] = max_s(q.k_s) - sum_s(q.k_s)/L ----------------
// block = (b,l), 512 threads = 8 waves (one per head); lane = sample index.
__global__ __launch_bounds__(512) void k_sample_scores(
    const float* __restrict__ Q, const float* __restrict__ K,
    const int* __restrict__ idxs, float* __restrict__ M)
{
  __shared__ float qs[H_ * D_];
  int bl = blockIdx.x;
  int b = bl >> 12;        // / L_
  int l = bl & (L_ - 1);
  int tid = threadIdx.x;
  qs[tid] = Q[(size_t)bl * (H_ * D_) + tid];
  __syncthreads();
  int h = tid >> 6;
  int lane = tid & 63;
  int s = lane < S_ ? lane : S_ - 1;
  bool valid = lane < S_;
  int idx = idxs[l * S_ + s];
  const float4* krow = (const float4*)K + ((size_t)(b * L_ + idx) * H_ + h) * (D_ / 4);
  const float4* q4 = (const float4*)qs + h * (D_ / 4);
  float acc = 0.f;
  #pragma unroll
  for (int d4 = 0; d4 < D_ / 4; ++d4) {
    float4 kv = krow[d4];
    float4 qv = q4[d4];
    acc = fmaf(qv.x, kv.x, acc);
    acc = fmaf(qv.y, kv.y, acc);
    acc = fmaf(qv.z, kv.z, acc);
    acc = fmaf(qv.w, kv.w, acc);
  }
  float vmax = valid ? acc : -FLT_MAX;
  float vsum = valid ? acc : 0.f;
  #pragma unroll
  for (int m = 32; m >= 1; m >>= 1) {
    vmax = fmaxf(vmax, __shfl_xor(vmax, m, 64));
    vsum += __shfl_xor(vsum, m, 64);
  }
  if (lane == 0)
    M[(size_t)(b * H_ + h) * L_ + l] = vmax - vsum * (1.0f / L_);
}

// ---------------- K2: top-45 indices per (b,h), tie -> smaller index ----------
__global__ __launch_bounds__(256) void k_topk(
    const float* __restrict__ M, int* __restrict__ mtop)
{
  __shared__ float mv[L_];
  __shared__ float rv[256];
  __shared__ int   ri[256];
  int bh = blockIdx.x;
  int tid = threadIdx.x;
  for (int i = tid; i < L_; i += 256) mv[i] = M[(size_t)bh * L_ + i];
  __syncthreads();
  for (int it = 0; it < S_; ++it) {
    float bv = -FLT_MAX; int bi = L_;
    for (int i = tid; i < L_; i += 256) {
      float v = mv[i];
      if (v > bv) { bv = v; bi = i; }   // ascending i: ties keep smaller index
    }
    rv[tid] = bv; ri[tid] = bi;
    __syncthreads();
    for (int st = 128; st > 0; st >>= 1) {
      if (tid < st) {
        float ov = rv[tid + st]; int oi = ri[tid + st];
        if (ov > rv[tid] || (ov == rv[tid] && oi < ri[tid])) { rv[tid] = ov; ri[tid] = oi; }
      }
      __syncthreads();
    }
    if (tid == 0) { mtop[bh * S_ + it] = ri[0]; mv[ri[0]] = -FLT_MAX; }
    __syncthreads();
  }
}

// ---------------- K3: per-chunk column sums of V (chunk = 64 rows) ------------
__global__ __launch_bounds__(256) void k_csum_chunks(
    const float* __restrict__ V, float* __restrict__ cs)
{
  int blk = blockIdx.x;          // B*H*16
  int bh = blk >> 4;
  int cg = blk & 15;
  int b = bh >> 3, h = bh & 7;
  int w = threadIdx.x >> 6, d = threadIdx.x & 63;
  int c = cg * 4 + w;
  const float* vp = V + ((size_t)(b * L_ + c * 64) * H_ + h) * D_ + d;
  float sum = 0.f;
  for (int i = 0; i < 64; ++i) sum += vp[(size_t)i * (H_ * D_)];
  cs[((size_t)bh * 64 + c) * D_ + d] = sum;
}

// ---------------- K4: exclusive scan of chunk sums over c ---------------------
__global__ __launch_bounds__(256) void k_csum_scan(float* __restrict__ cs)
{
  int g = blockIdx.x * 256 + threadIdx.x;   // 2048 threads total
  int bh = g >> 6, d = g & 63;
  float run = 0.f;
  for (int c = 0; c < 64; ++c) {
    size_t off = ((size_t)bh * 64 + c) * D_ + d;
    float a = cs[off];
    cs[off] = run;
    run += a;
  }
}

// ---------------- K5: final cumsum write --------------------------------------
__global__ __launch_bounds__(256) void k_csum_write(
    const float* __restrict__ V, const float* __restrict__ cs,
    float* __restrict__ out)
{
  int blk = blockIdx.x;
  int bh = blk >> 4, cg = blk & 15;
  int b = bh >> 3, h = bh & 7;
  int w = threadIdx.x >> 6, d = threadIdx.x & 63;
  int c = cg * 4 + w;
  int l0 = c * 64;
  const float* vp = V + ((size_t)(b * L_ + l0) * H_ + h) * D_ + d;
  float run = cs[((size_t)bh * 64 + c) * D_ + d];
  float* op = out + ((size_t)bh * L_ + l0) * D_ + d;
  for (int i = 0; i < 64; ++i) {
    run += vp[(size_t)i * (H_ * D_)];
    op[(size_t)i * D_] = run;
  }
}

// ---------------- K6: attention partials (unnormalized) -----------------------
// block = (b,h, k-chunk of 256). Computes e = exp(score) with causal mask,
// partial softmax denominators and partial un-normalized updates.
__global__ __launch_bounds__(256) void k_attn_partial(
    const float* __restrict__ Q, const float* __restrict__ K,
    const float* __restrict__ V, const int* __restrict__ mtop,
    float* __restrict__ lpart, float* __restrict__ updp)
{
  __shared__ float qr[S_ * D_];      // 11.25 KB
  __shared__ float el[S_ * KCH_];    // 45 KB  (reused as cross-wave scratch)
  __shared__ float lred[4 * S_];
  __shared__ int   cut[S_];
  int blk = blockIdx.x;
  int bh = blk >> 4;                 // / KC_
  int kc = blk & 15;
  int b = bh >> 3, h = bh & 7;
  int tid = threadIdx.x;
  if (tid < S_) cut[tid] = mtop[bh * S_ + tid];
  __syncthreads();
  for (int i = tid; i < S_ * D_; i += 256) {
    int r = i >> 6, d = i & 63;
    qr[i] = Q[((size_t)(b * L_ + cut[r]) * H_ + h) * D_ + d];
  }
  __syncthreads();

  // phase A: scores -> e
  int k = kc * KCH_ + tid;
  float acc[S_];
  #pragma unroll
  for (int r = 0; r < S_; ++r) acc[r] = 0.f;
  const float4* krow = (const float4*)K + ((size_t)(b * L_ + k) * H_ + h) * (D_ / 4);
  const float4* qr4 = (const float4*)qr;
  for (int d4 = 0; d4 < D_ / 4; ++d4) {
    float4 kv = krow[d4];
    #pragma unroll
    for (int r = 0; r < S_; ++r) {
      float4 qv = qr4[r * (D_ / 4) + d4];
      acc[r] = fmaf(qv.x, kv.x, acc[r]);
      acc[r] = fmaf(qv.y, kv.y, acc[r]);
      acc[r] = fmaf(qv.z, kv.z, acc[r]);
      acc[r] = fmaf(qv.w, kv.w, acc[r]);
    }
  }
  #pragma unroll
  for (int r = 0; r < S_; ++r) {
    float e = (k <= cut[r]) ? __expf(acc[r] * SCALE) : 0.f;
    el[r * KCH_ + tid] = e;
    acc[r] = e;
  }
  // partial softmax denominators
  int w = tid >> 6, lane = tid & 63;
  #pragma unroll
  for (int r = 0; r < S_; ++r) {
    float v = acc[r];
    #pragma unroll
    for (int m = 32; m >= 1; m >>= 1) v += __shfl_xor(v, m, 64);
    if (lane == 0) lred[w * S_ + r] = v;
  }
  __syncthreads();
  if (tid < S_)
    lpart[(size_t)blk * S_ + tid] =
        lred[tid] + lred[S_ + tid] + lred[2 * S_ + tid] + lred[3 * S_ + tid];

  // phase B: partial update = e @ V over this chunk
  float acc2[S_];
  #pragma unroll
  for (int r = 0; r < S_; ++r) acc2[r] = 0.f;
  int d = lane;
  const float* vp = V + ((size_t)(b * L_ + kc * KCH_) * H_ + h) * D_ + d;
  for (int kk = 0; kk < 16; ++kk) {
    int kb = w * 64 + kk * 4;
    float v0 = vp[(size_t)(kb + 0) * (H_ * D_)];
    float v1 = vp[(size_t)(kb + 1) * (H_ * D_)];
    float v2 = vp[(size_t)(kb + 2) * (H_ * D_)];
    float v3 = vp[(size_t)(kb + 3) * (H_ * D_)];
    #pragma unroll
    for (int r = 0; r < S_; ++r) {
      float4 e4 = *(const float4*)&el[r * KCH_ + kb];
      acc2[r] = fmaf(e4.x, v0, acc2[r]);
      acc2[r] = fmaf(e4.y, v1, acc2[r]);
      acc2[r] = fmaf(e4.z, v2, acc2[r]);
      acc2[r] = fmaf(e4.w, v3, acc2[r]);
    }
  }
  __syncthreads();   // all reads of el done
  #pragma unroll
  for (int r = 0; r < S_; ++r) el[w * (S_ * D_) + r * D_ + d] = acc2[r];
  __syncthreads();
  for (int i = tid; i < S_ * D_; i += 256) {
    float s = el[i] + el[S_ * D_ + i] + el[2 * S_ * D_ + i] + el[3 * S_ * D_ + i];
    updp[(size_t)blk * (S_ * D_) + i] = s;
  }
}

// ---------------- K7: reduce partials, normalize, scatter over cumsum ---------
__global__ __launch_bounds__(256) void k_finalize(
    const float* __restrict__ lpart, const float* __restrict__ updp,
    const int* __restrict__ mtop, float* __restrict__ out)
{
  __shared__ float linv[S_];
  __shared__ int   mt[S_];
  int bh = blockIdx.x;
  int tid = threadIdx.x;
  if (tid < S_) {
    float l = 0.f;
    for (int kc = 0; kc < KC_; ++kc) l += lpart[(size_t)(bh * KC_ + kc) * S_ + tid];
    linv[tid] = 1.0f / l;
    mt[tid] = mtop[bh * S_ + tid];
  }
  __syncthreads();
  for (int i = tid; i < S_ * D_; i += 256) {
    int r = i >> 6, d = i & 63;
    float u = 0.f;
    for (int kc = 0; kc < KC_; ++kc) u += updp[((size_t)(bh * KC_ + kc)) * (S_ * D_) + i];
    out[((size_t)bh * L_ + mt[r]) * D_ + d] = u * linv[r];
  }
}

extern "C" void kernel_launch(void* const* d_in, const int* in_sizes, int n_in,
                              void* d_out, int out_size, void* d_ws, size_t ws_size,
                              hipStream_t stream) {
  const float* Q = (const float*)d_in[0];
  const float* K = (const float*)d_in[1];
  const float* V = (const float*)d_in[2];
  const int*   I = (const int*)d_in[3];
  float* out = (float*)d_out;
  float* ws = (float*)d_ws;

  float* M     = ws;                       // 131072 floats
  float* cs    = ws + 131072;              // 131072 floats
  float* lpart = ws + 262144;              // 32*16*45 = 23040 floats
  float* updp  = ws + 262144 + 23040;      // 32*16*45*64 = 1474560 floats
  int*   mtop  = (int*)(ws + 262144 + 23040 + 1474560);   // 1440 ints

  k_sample_scores<<<B_ * L_, 512, 0, stream>>>(Q, K, I, M);
  k_topk<<<B_ * H_, 256, 0, stream>>>(M, mtop);
  k_csum_chunks<<<B_ * H_ * 16, 256, 0, stream>>>(V, cs);
  k_csum_scan<<<8, 256, 0, stream>>>(cs);
  k_csum_write<<<B_ * H_ * 16, 256, 0, stream>>>(V, cs, out);
  k_attn_partial<<<B_ * H_ * KC_, 256, 0, stream>>>(Q, K, V, mtop, lpart, updp);
  k_finalize<<<B_ * H_, 256, 0, stream>>>(lpart, updp, mtop, out);
}

// Round 2
// 384.940 us; speedup vs baseline: 1.0990x; 1.0990x over previous
//
#include <hip/hip_runtime.h>
#include <float.h>
#include <math.h>

#define B_ 4
#define L_ 4096
#define H_ 8
#define D_ 64
#define S_ 45      // sample_k == u == 45
#define KC_ 16     // k-chunks for attention pass
#define KCH_ 256   // k per chunk
#define SCALE 0.125f

// ---------------- K1: M[b,h,l] = max_s(q.k_s) - sum_s(q.k_s)/L ----------------
// block = (bh, l-chunk of 4). blockIdx%32 == bh so XCD = bh%8 is FIXED per
// (b,h): each XCD's L2 holds 4 K-slices (4 x 1MB) -> gather becomes L2-hit.
__global__ __launch_bounds__(256) void k_sample_scores(
    const float* __restrict__ Q, const float* __restrict__ K,
    const int* __restrict__ idxs, float* __restrict__ M)
{
  __shared__ float qs[4][D_];
  int blk = blockIdx.x;
  int bh = blk & 31;          // XCD-pinned
  int chunk = blk >> 5;       // 0..L/4-1
  int b = bh >> 3, h = bh & 7;
  int tid = threadIdx.x;
  int w = tid >> 6, lane = tid & 63;
  int l = chunk * 4 + w;
  qs[w][lane] = Q[((size_t)(b * L_ + l) * H_ + h) * D_ + lane];
  __syncthreads();
  int s = lane < S_ ? lane : S_ - 1;
  bool valid = lane < S_;
  int idx = idxs[l * S_ + s];
  const float4* krow = (const float4*)K + ((size_t)(b * L_ + idx) * H_ + h) * (D_ / 4);
  const float4* q4 = (const float4*)qs[w];
  float acc = 0.f;
  #pragma unroll
  for (int d4 = 0; d4 < D_ / 4; ++d4) {
    float4 kv = krow[d4];
    float4 qv = q4[d4];
    acc = fmaf(qv.x, kv.x, acc);
    acc = fmaf(qv.y, kv.y, acc);
    acc = fmaf(qv.z, kv.z, acc);
    acc = fmaf(qv.w, kv.w, acc);
  }
  float vmax = valid ? acc : -FLT_MAX;
  float vsum = valid ? acc : 0.f;
  #pragma unroll
  for (int m = 32; m >= 1; m >>= 1) {
    vmax = fmaxf(vmax, __shfl_xor(vmax, m, 64));
    vsum += __shfl_xor(vsum, m, 64);
  }
  if (lane == 0)
    M[(size_t)(b * H_ + h) * L_ + l] = vmax - vsum * (1.0f / L_);
}

// ---------------- K2: top-45 per (b,h), register-resident selection -----------
// Packed key = (ordered_float(v) << 32) | ~idx : max key == max value with
// ties broken toward the SMALLER index (matches lax.top_k).
__device__ __forceinline__ unsigned ordf(float f) {
  unsigned u = __float_as_uint(f);
  return (u & 0x80000000u) ? ~u : (u | 0x80000000u);
}

__global__ __launch_bounds__(256) void k_topk(
    const float* __restrict__ M, int* __restrict__ mtop)
{
  __shared__ unsigned long long cand[4][S_];
  int bh = blockIdx.x;
  int tid = threadIdx.x, w = tid >> 6, lane = tid & 63;
  const float* Mp = M + (size_t)bh * L_;
  unsigned long long key[16];
  #pragma unroll
  for (int j = 0; j < 16; ++j) {
    int gi = w * 1024 + j * 64 + lane;
    key[j] = ((unsigned long long)ordf(Mp[gi]) << 32) | (unsigned)(~gi);
  }
  // per-wave top-45 of its 1024 elements
  for (int it = 0; it < S_; ++it) {
    unsigned long long loc = key[0];
    #pragma unroll
    for (int j = 1; j < 16; ++j) loc = key[j] > loc ? key[j] : loc;
    unsigned long long best = loc;
    #pragma unroll
    for (int m = 32; m >= 1; m >>= 1) {
      unsigned long long o = __shfl_xor(best, m, 64);
      best = o > best ? o : best;
    }
    if (loc == best) {   // unique owner (keys contain unique idx)
      #pragma unroll
      for (int j = 0; j < 16; ++j) if (key[j] == best) key[j] = 0ull;
    }
    if (lane == 0) cand[w][it] = best;
  }
  __syncthreads();
  // wave 0 merges the 4x45 candidates
  if (w == 0) {
    unsigned long long k2[3];
    #pragma unroll
    for (int j = 0; j < 3; ++j) {
      int c = j * 64 + lane;
      k2[j] = (c < 4 * S_) ? cand[c / S_][c % S_] : 0ull;
    }
    for (int it = 0; it < S_; ++it) {
      unsigned long long loc = k2[0];
      loc = k2[1] > loc ? k2[1] : loc;
      loc = k2[2] > loc ? k2[2] : loc;
      unsigned long long best = loc;
      #pragma unroll
      for (int m = 32; m >= 1; m >>= 1) {
        unsigned long long o = __shfl_xor(best, m, 64);
        best = o > best ? o : best;
      }
      if (loc == best) {
        #pragma unroll
        for (int j = 0; j < 3; ++j) if (k2[j] == best) k2[j] = 0ull;
      }
      if (lane == 0) mtop[bh * S_ + it] = (int)(~(unsigned)(best & 0xFFFFFFFFu));
    }
  }
}

// ---------------- K3: per-chunk column sums of V (chunk = 64 rows) ------------
__global__ __launch_bounds__(256) void k_csum_chunks(
    const float* __restrict__ V, float* __restrict__ cs)
{
  int blk = blockIdx.x;          // B*H*16
  int bh = blk >> 4;
  int cg = blk & 15;
  int b = bh >> 3, h = bh & 7;
  int w = threadIdx.x >> 6, d = threadIdx.x & 63;
  int c = cg * 4 + w;
  const float* vp = V + ((size_t)(b * L_ + c * 64) * H_ + h) * D_ + d;
  float sum = 0.f;
  for (int i = 0; i < 64; ++i) sum += vp[(size_t)i * (H_ * D_)];
  cs[((size_t)bh * 64 + c) * D_ + d] = sum;
}

// ---------------- K4: exclusive scan of chunk sums over c ---------------------
__global__ __launch_bounds__(256) void k_csum_scan(float* __restrict__ cs)
{
  int g = blockIdx.x * 256 + threadIdx.x;   // 2048 threads total
  int bh = g >> 6, d = g & 63;
  float run = 0.f;
  for (int c = 0; c < 64; ++c) {
    size_t off = ((size_t)bh * 64 + c) * D_ + d;
    float a = cs[off];
    cs[off] = run;
    run += a;
  }
}

// ---------------- K5: final cumsum write --------------------------------------
__global__ __launch_bounds__(256) void k_csum_write(
    const float* __restrict__ V, const float* __restrict__ cs,
    float* __restrict__ out)
{
  int blk = blockIdx.x;
  int bh = blk >> 4, cg = blk & 15;
  int b = bh >> 3, h = bh & 7;
  int w = threadIdx.x >> 6, d = threadIdx.x & 63;
  int c = cg * 4 + w;
  int l0 = c * 64;
  const float* vp = V + ((size_t)(b * L_ + l0) * H_ + h) * D_ + d;
  float run = cs[((size_t)bh * 64 + c) * D_ + d];
  float* op = out + ((size_t)bh * L_ + l0) * D_ + d;
  for (int i = 0; i < 64; ++i) {
    run += vp[(size_t)i * (H_ * D_)];
    op[(size_t)i * D_] = run;
  }
}

// ---------------- K6: attention partials (unnormalized) -----------------------
__global__ __launch_bounds__(256) void k_attn_partial(
    const float* __restrict__ Q, const float* __restrict__ K,
    const float* __restrict__ V, const int* __restrict__ mtop,
    float* __restrict__ lpart, float* __restrict__ updp)
{
  __shared__ float qr[S_ * D_];      // 11.25 KB
  __shared__ float el[S_ * KCH_];    // 45 KB  (reused as cross-wave scratch)
  __shared__ float lred[4 * S_];
  __shared__ int   cut[S_];
  int blk = blockIdx.x;
  int bh = blk >> 4;                 // / KC_
  int kc = blk & 15;
  int b = bh >> 3, h = bh & 7;
  int tid = threadIdx.x;
  if (tid < S_) cut[tid] = mtop[bh * S_ + tid];
  __syncthreads();
  for (int i = tid; i < S_ * D_; i += 256) {
    int r = i >> 6, d = i & 63;
    qr[i] = Q[((size_t)(b * L_ + cut[r]) * H_ + h) * D_ + d];
  }
  __syncthreads();

  // phase A: scores -> e
  int k = kc * KCH_ + tid;
  float acc[S_];
  #pragma unroll
  for (int r = 0; r < S_; ++r) acc[r] = 0.f;
  const float4* krow = (const float4*)K + ((size_t)(b * L_ + k) * H_ + h) * (D_ / 4);
  const float4* qr4 = (const float4*)qr;
  for (int d4 = 0; d4 < D_ / 4; ++d4) {
    float4 kv = krow[d4];
    #pragma unroll
    for (int r = 0; r < S_; ++r) {
      float4 qv = qr4[r * (D_ / 4) + d4];
      acc[r] = fmaf(qv.x, kv.x, acc[r]);
      acc[r] = fmaf(qv.y, kv.y, acc[r]);
      acc[r] = fmaf(qv.z, kv.z, acc[r]);
      acc[r] = fmaf(qv.w, kv.w, acc[r]);
    }
  }
  #pragma unroll
  for (int r = 0; r < S_; ++r) {
    float e = (k <= cut[r]) ? __expf(acc[r] * SCALE) : 0.f;
    el[r * KCH_ + tid] = e;
    acc[r] = e;
  }
  // partial softmax denominators
  int w = tid >> 6, lane = tid & 63;
  #pragma unroll
  for (int r = 0; r < S_; ++r) {
    float v = acc[r];
    #pragma unroll
    for (int m = 32; m >= 1; m >>= 1) v += __shfl_xor(v, m, 64);
    if (lane == 0) lred[w * S_ + r] = v;
  }
  __syncthreads();
  if (tid < S_)
    lpart[(size_t)blk * S_ + tid] =
        lred[tid] + lred[S_ + tid] + lred[2 * S_ + tid] + lred[3 * S_ + tid];

  // phase B: partial update = e @ V over this chunk
  float acc2[S_];
  #pragma unroll
  for (int r = 0; r < S_; ++r) acc2[r] = 0.f;
  int d = lane;
  const float* vp = V + ((size_t)(b * L_ + kc * KCH_) * H_ + h) * D_ + d;
  for (int kk = 0; kk < 16; ++kk) {
    int kb = w * 64 + kk * 4;
    float v0 = vp[(size_t)(kb + 0) * (H_ * D_)];
    float v1 = vp[(size_t)(kb + 1) * (H_ * D_)];
    float v2 = vp[(size_t)(kb + 2) * (H_ * D_)];
    float v3 = vp[(size_t)(kb + 3) * (H_ * D_)];
    #pragma unroll
    for (int r = 0; r < S_; ++r) {
      float4 e4 = *(const float4*)&el[r * KCH_ + kb];
      acc2[r] = fmaf(e4.x, v0, acc2[r]);
      acc2[r] = fmaf(e4.y, v1, acc2[r]);
      acc2[r] = fmaf(e4.z, v2, acc2[r]);
      acc2[r] = fmaf(e4.w, v3, acc2[r]);
    }
  }
  __syncthreads();   // all reads of el done
  #pragma unroll
  for (int r = 0; r < S_; ++r) el[w * (S_ * D_) + r * D_ + d] = acc2[r];
  __syncthreads();
  for (int i = tid; i < S_ * D_; i += 256) {
    float s = el[i] + el[S_ * D_ + i] + el[2 * S_ * D_ + i] + el[3 * S_ * D_ + i];
    updp[(size_t)blk * (S_ * D_) + i] = s;
  }
}

// ---------------- K7: reduce partials, normalize, scatter over cumsum ---------
__global__ __launch_bounds__(256) void k_finalize(
    const float* __restrict__ lpart, const float* __restrict__ updp,
    const int* __restrict__ mtop, float* __restrict__ out)
{
  __shared__ float linv[S_];
  __shared__ int   mt[S_];
  int bh = blockIdx.x;
  int tid = threadIdx.x;
  if (tid < S_) {
    float l = 0.f;
    for (int kc = 0; kc < KC_; ++kc) l += lpart[(size_t)(bh * KC_ + kc) * S_ + tid];
    linv[tid] = 1.0f / l;
    mt[tid] = mtop[bh * S_ + tid];
  }
  __syncthreads();
  for (int i = tid; i < S_ * D_; i += 256) {
    int r = i >> 6, d = i & 63;
    float u = 0.f;
    for (int kc = 0; kc < KC_; ++kc) u += updp[((size_t)(bh * KC_ + kc)) * (S_ * D_) + i];
    out[((size_t)bh * L_ + mt[r]) * D_ + d] = u * linv[r];
  }
}

extern "C" void kernel_launch(void* const* d_in, const int* in_sizes, int n_in,
                              void* d_out, int out_size, void* d_ws, size_t ws_size,
                              hipStream_t stream) {
  const float* Q = (const float*)d_in[0];
  const float* K = (const float*)d_in[1];
  const float* V = (const float*)d_in[2];
  const int*   I = (const int*)d_in[3];
  float* out = (float*)d_out;
  float* ws = (float*)d_ws;

  float* M     = ws;                       // 131072 floats
  float* cs    = ws + 131072;              // 131072 floats
  float* lpart = ws + 262144;              // 32*16*45 = 23040 floats
  float* updp  = ws + 262144 + 23040;      // 32*16*45*64 = 1474560 floats
  int*   mtop  = (int*)(ws + 262144 + 23040 + 1474560);   // 1440 ints

  k_sample_scores<<<(L_ / 4) * B_ * H_, 256, 0, stream>>>(Q, K, I, M);
  k_topk<<<B_ * H_, 256, 0, stream>>>(M, mtop);
  k_csum_chunks<<<B_ * H_ * 16, 256, 0, stream>>>(V, cs);
  k_csum_scan<<<8, 256, 0, stream>>>(cs);
  k_csum_write<<<B_ * H_ * 16, 256, 0, stream>>>(V, cs, out);
  k_attn_partial<<<B_ * H_ * KC_, 256, 0, stream>>>(Q, K, V, mtop, lpart, updp);
  k_finalize<<<B_ * H_, 256, 0, stream>>>(lpart, updp, mtop, out);
}

// Round 4
// 249.419 us; speedup vs baseline: 1.6961x; 1.5433x over previous
//
#include <hip/hip_runtime.h>
#include <float.h>
#include <math.h>

#define B_ 4
#define L_ 4096
#define H_ 8
#define D_ 64
#define S_ 45      // sample_k == u == 45
#define NS_ 12     // ceil(S_/4) row-steps per wave
#define KC_ 16     // k-chunks for attention pass
#define KCH_ 256   // k per chunk
#define SCALE 0.125f

// ---------------- K1: M[b,h,l] = max_s(q.k_s) - sum_s(q.k_s)/L ----------------
// blockIdx%32 == bh -> XCD pinned (4 x 1MB K-slices per XCD L2).
// One query per wave; 16 lanes cooperate on each K-row (lane t reads float4 #t)
// -> coalesced 256B row segments, ~4x fewer unique cachelines per instruction.
// All 12 row loads (48 VGPRs) issued before any use.
__global__ __launch_bounds__(256) void k_sample_scores(
    const float* __restrict__ Q, const float* __restrict__ K,
    const int* __restrict__ idxs, float* __restrict__ M)
{
  int blk = blockIdx.x;
  int bh = blk & 31;             // XCD-pinned
  int chunk = blk >> 5;          // 0..L/4-1
  int b = bh >> 3, h = bh & 7;
  int tid = threadIdx.x;
  int w = tid >> 6, lane = tid & 63;
  int slot = lane >> 4, t = lane & 15;
  int l = chunk * 4 + w;

  // q-row l: lane t of each 16-lane slot group holds float4 #t (broadcast x4)
  const float4* qrow = (const float4*)(Q + ((size_t)(b * L_ + l) * H_ + h) * D_);
  float4 qv = qrow[t];

  // all 45 sample indices: lane s holds idxs[l][s]
  int s = lane < S_ ? lane : S_ - 1;
  int idxall = idxs[l * S_ + s];

  // broadcast row indices for the 12 steps (4 rows per step, one per slot)
  int kidx[NS_];
  #pragma unroll
  for (int i = 0; i < NS_; ++i) {
    int r = i * 4 + slot;
    int rr = r < S_ ? r : S_ - 1;
    kidx[i] = __shfl(idxall, rr, 64);
  }
  // issue all 12 coalesced row loads before any use
  float4 kv[NS_];
  #pragma unroll
  for (int i = 0; i < NS_; ++i) {
    const float4* krow =
        (const float4*)(K + ((size_t)(b * L_ + kidx[i]) * H_ + h) * D_);
    kv[i] = krow[t];
  }

  float vmax = -FLT_MAX, vsum = 0.f;
  #pragma unroll
  for (int i = 0; i < NS_; ++i) {
    float p = qv.x * kv[i].x;
    p = fmaf(qv.y, kv[i].y, p);
    p = fmaf(qv.z, kv[i].z, p);
    p = fmaf(qv.w, kv[i].w, p);
    // 16-lane group sum -> every lane of the group holds the full row dot
    p += __shfl_xor(p, 1, 64);
    p += __shfl_xor(p, 2, 64);
    p += __shfl_xor(p, 4, 64);
    p += __shfl_xor(p, 8, 64);
    int r = i * 4 + slot;
    if (t == 0 && r < S_) { vmax = fmaxf(vmax, p); vsum += p; }
  }
  #pragma unroll
  for (int m = 32; m >= 1; m >>= 1) {
    vmax = fmaxf(vmax, __shfl_xor(vmax, m, 64));
    vsum += __shfl_xor(vsum, m, 64);
  }
  if (lane == 0)
    M[(size_t)bh * L_ + l] = vmax - vsum * (1.0f / L_);
}

// ---------------- K2: top-45 per (b,h), register-resident selection -----------
__device__ __forceinline__ unsigned ordf(float f) {
  unsigned u = __float_as_uint(f);
  return (u & 0x80000000u) ? ~u : (u | 0x80000000u);
}

__global__ __launch_bounds__(256) void k_topk(
    const float* __restrict__ M, int* __restrict__ mtop)
{
  __shared__ unsigned long long cand[4][S_];
  int bh = blockIdx.x;
  int tid = threadIdx.x, w = tid >> 6, lane = tid & 63;
  const float* Mp = M + (size_t)bh * L_;
  unsigned long long key[16];
  #pragma unroll
  for (int j = 0; j < 16; ++j) {
    int gi = w * 1024 + j * 64 + lane;
    key[j] = ((unsigned long long)ordf(Mp[gi]) << 32) | (unsigned)(~gi);
  }
  for (int it = 0; it < S_; ++it) {
    unsigned long long loc = key[0];
    #pragma unroll
    for (int j = 1; j < 16; ++j) loc = key[j] > loc ? key[j] : loc;
    unsigned long long best = loc;
    #pragma unroll
    for (int m = 32; m >= 1; m >>= 1) {
      unsigned long long o = __shfl_xor(best, m, 64);
      best = o > best ? o : best;
    }
    if (loc == best) {
      #pragma unroll
      for (int j = 0; j < 16; ++j) if (key[j] == best) key[j] = 0ull;
    }
    if (lane == 0) cand[w][it] = best;
  }
  __syncthreads();
  if (w == 0) {
    unsigned long long k2[3];
    #pragma unroll
    for (int j = 0; j < 3; ++j) {
      int c = j * 64 + lane;
      k2[j] = (c < 4 * S_) ? cand[c / S_][c % S_] : 0ull;
    }
    for (int it = 0; it < S_; ++it) {
      unsigned long long loc = k2[0];
      loc = k2[1] > loc ? k2[1] : loc;
      loc = k2[2] > loc ? k2[2] : loc;
      unsigned long long best = loc;
      #pragma unroll
      for (int m = 32; m >= 1; m >>= 1) {
        unsigned long long o = __shfl_xor(best, m, 64);
        best = o > best ? o : best;
      }
      if (loc == best) {
        #pragma unroll
        for (int j = 0; j < 3; ++j) if (k2[j] == best) k2[j] = 0ull;
      }
      if (lane == 0) mtop[bh * S_ + it] = (int)(~(unsigned)(best & 0xFFFFFFFFu));
    }
  }
}

// ---------------- K3: per-chunk column sums of V (chunk = 64 rows) ------------
__global__ __launch_bounds__(256) void k_csum_chunks(
    const float* __restrict__ V, float* __restrict__ cs)
{
  int blk = blockIdx.x;          // B*H*16
  int bh = blk >> 4;
  int cg = blk & 15;
  int b = bh >> 3, h = bh & 7;
  int w = threadIdx.x >> 6, d = threadIdx.x & 63;
  int c = cg * 4 + w;
  const float* vp = V + ((size_t)(b * L_ + c * 64) * H_ + h) * D_ + d;
  float sum = 0.f;
  for (int i = 0; i < 64; ++i) sum += vp[(size_t)i * (H_ * D_)];
  cs[((size_t)bh * 64 + c) * D_ + d] = sum;
}

// ---------------- K4: exclusive scan of chunk sums over c ---------------------
__global__ __launch_bounds__(256) void k_csum_scan(float* __restrict__ cs)
{
  int g = blockIdx.x * 256 + threadIdx.x;   // 2048 threads total
  int bh = g >> 6, d = g & 63;
  float run = 0.f;
  for (int c = 0; c < 64; ++c) {
    size_t off = ((size_t)bh * 64 + c) * D_ + d;
    float a = cs[off];
    cs[off] = run;
    run += a;
  }
}

// ---------------- K5: final cumsum write --------------------------------------
__global__ __launch_bounds__(256) void k_csum_write(
    const float* __restrict__ V, const float* __restrict__ cs,
    float* __restrict__ out)
{
  int blk = blockIdx.x;
  int bh = blk >> 4, cg = blk & 15;
  int b = bh >> 3, h = bh & 7;
  int w = threadIdx.x >> 6, d = threadIdx.x & 63;
  int c = cg * 4 + w;
  int l0 = c * 64;
  const float* vp = V + ((size_t)(b * L_ + l0) * H_ + h) * D_ + d;
  float run = cs[((size_t)bh * 64 + c) * D_ + d];
  float* op = out + ((size_t)bh * L_ + l0) * D_ + d;
  for (int i = 0; i < 64; ++i) {
    run += vp[(size_t)i * (H_ * D_)];
    op[(size_t)i * D_] = run;
  }
}

// ---------------- K6: attention partials (unnormalized) -----------------------
__global__ __launch_bounds__(256) void k_attn_partial(
    const float* __restrict__ Q, const float* __restrict__ K,
    const float* __restrict__ V, const int* __restrict__ mtop,
    float* __restrict__ lpart, float* __restrict__ updp)
{
  __shared__ float qr[S_ * D_];      // 11.25 KB
  __shared__ float el[S_ * KCH_];    // 45 KB  (reused as cross-wave scratch)
  __shared__ float lred[4 * S_];
  __shared__ int   cut[S_];
  int blk = blockIdx.x;
  int bh = blk >> 4;                 // / KC_
  int kc = blk & 15;
  int b = bh >> 3, h = bh & 7;
  int tid = threadIdx.x;
  if (tid < S_) cut[tid] = mtop[bh * S_ + tid];
  __syncthreads();
  for (int i = tid; i < S_ * D_; i += 256) {
    int r = i >> 6, d = i & 63;
    qr[i] = Q[((size_t)(b * L_ + cut[r]) * H_ + h) * D_ + d];
  }
  __syncthreads();

  // phase A: scores -> e
  int k = kc * KCH_ + tid;
  float acc[S_];
  #pragma unroll
  for (int r = 0; r < S_; ++r) acc[r] = 0.f;
  const float4* krow = (const float4*)K + ((size_t)(b * L_ + k) * H_ + h) * (D_ / 4);
  const float4* qr4 = (const float4*)qr;
  for (int d4 = 0; d4 < D_ / 4; ++d4) {
    float4 kv = krow[d4];
    #pragma unroll
    for (int r = 0; r < S_; ++r) {
      float4 qv = qr4[r * (D_ / 4) + d4];
      acc[r] = fmaf(qv.x, kv.x, acc[r]);
      acc[r] = fmaf(qv.y, kv.y, acc[r]);
      acc[r] = fmaf(qv.z, kv.z, acc[r]);
      acc[r] = fmaf(qv.w, kv.w, acc[r]);
    }
  }
  #pragma unroll
  for (int r = 0; r < S_; ++r) {
    float e = (k <= cut[r]) ? __expf(acc[r] * SCALE) : 0.f;
    el[r * KCH_ + tid] = e;
    acc[r] = e;
  }
  // partial softmax denominators
  int w = tid >> 6, lane = tid & 63;
  #pragma unroll
  for (int r = 0; r < S_; ++r) {
    float v = acc[r];
    #pragma unroll
    for (int m = 32; m >= 1; m >>= 1) v += __shfl_xor(v, m, 64);
    if (lane == 0) lred[w * S_ + r] = v;
  }
  __syncthreads();
  if (tid < S_)
    lpart[(size_t)blk * S_ + tid] =
        lred[tid] + lred[S_ + tid] + lred[2 * S_ + tid] + lred[3 * S_ + tid];

  // phase B: partial update = e @ V over this chunk
  float acc2[S_];
  #pragma unroll
  for (int r = 0; r < S_; ++r) acc2[r] = 0.f;
  int d = lane;
  const float* vp = V + ((size_t)(b * L_ + kc * KCH_) * H_ + h) * D_ + d;
  for (int kk = 0; kk < 16; ++kk) {
    int kb = w * 64 + kk * 4;
    float v0 = vp[(size_t)(kb + 0) * (H_ * D_)];
    float v1 = vp[(size_t)(kb + 1) * (H_ * D_)];
    float v2 = vp[(size_t)(kb + 2) * (H_ * D_)];
    float v3 = vp[(size_t)(kb + 3) * (H_ * D_)];
    #pragma unroll
    for (int r = 0; r < S_; ++r) {
      float4 e4 = *(const float4*)&el[r * KCH_ + kb];
      acc2[r] = fmaf(e4.x, v0, acc2[r]);
      acc2[r] = fmaf(e4.y, v1, acc2[r]);
      acc2[r] = fmaf(e4.z, v2, acc2[r]);
      acc2[r] = fmaf(e4.w, v3, acc2[r]);
    }
  }
  __syncthreads();   // all reads of el done
  #pragma unroll
  for (int r = 0; r < S_; ++r) el[w * (S_ * D_) + r * D_ + d] = acc2[r];
  __syncthreads();
  for (int i = tid; i < S_ * D_; i += 256) {
    float s = el[i] + el[S_ * D_ + i] + el[2 * S_ * D_ + i] + el[3 * S_ * D_ + i];
    updp[(size_t)blk * (S_ * D_) + i] = s;
  }
}

// ---------------- K7: reduce partials, normalize, scatter over cumsum ---------
__global__ __launch_bounds__(256) void k_finalize(
    const float* __restrict__ lpart, const float* __restrict__ updp,
    const int* __restrict__ mtop, float* __restrict__ out)
{
  __shared__ float linv[S_];
  __shared__ int   mt[S_];
  int bh = blockIdx.x;
  int tid = threadIdx.x;
  if (tid < S_) {
    float l = 0.f;
    for (int kc = 0; kc < KC_; ++kc) l += lpart[(size_t)(bh * KC_ + kc) * S_ + tid];
    linv[tid] = 1.0f / l;
    mt[tid] = mtop[bh * S_ + tid];
  }
  __syncthreads();
  for (int i = tid; i < S_ * D_; i += 256) {
    int r = i >> 6, d = i & 63;
    float u = 0.f;
    for (int kc = 0; kc < KC_; ++kc) u += updp[((size_t)(bh * KC_ + kc)) * (S_ * D_) + i];
    out[((size_t)bh * L_ + mt[r]) * D_ + d] = u * linv[r];
  }
}

extern "C" void kernel_launch(void* const* d_in, const int* in_sizes, int n_in,
                              void* d_out, int out_size, void* d_ws, size_t ws_size,
                              hipStream_t stream) {
  const float* Q = (const float*)d_in[0];
  const float* K = (const float*)d_in[1];
  const float* V = (const float*)d_in[2];
  const int*   I = (const int*)d_in[3];
  float* out = (float*)d_out;
  float* ws = (float*)d_ws;

  float* M     = ws;                       // 131072 floats
  float* cs    = ws + 131072;              // 131072 floats
  float* lpart = ws + 262144;              // 32*16*45 = 23040 floats
  float* updp  = ws + 262144 + 23040;      // 32*16*45*64 = 1474560 floats
  int*   mtop  = (int*)(ws + 262144 + 23040 + 1474560);   // 1440 ints

  k_sample_scores<<<(L_ / 4) * B_ * H_, 256, 0, stream>>>(Q, K, I, M);
  k_topk<<<B_ * H_, 256, 0, stream>>>(M, mtop);
  k_csum_chunks<<<B_ * H_ * 16, 256, 0, stream>>>(V, cs);
  k_csum_scan<<<8, 256, 0, stream>>>(cs);
  k_csum_write<<<B_ * H_ * 16, 256, 0, stream>>>(V, cs, out);
  k_attn_partial<<<B_ * H_ * KC_, 256, 0, stream>>>(Q, K, V, mtop, lpart, updp);
  k_finalize<<<B_ * H_, 256, 0, stream>>>(lpart, updp, mtop, out);
}

// Round 5
// 231.059 us; speedup vs baseline: 1.8309x; 1.0795x over previous
//
#include <hip/hip_runtime.h>
#include <float.h>
#include <math.h>

#define B_ 4
#define L_ 4096
#define H_ 8
#define D_ 64
#define S_ 45      // sample_k == u == 45
#define KC_ 16     // k-chunks for attention pass
#define KCH_ 256   // k per chunk
#define SCALE 0.125f

// ---------------- K1: M[b,h,l] = max_s(q.k_s) - sum_s(q.k_s)/L ----------------
// 4-head-fused gather. Group g=(b,hhalf) in [0,8): blk%8==g -> XCD g holds the
// 4MB slice K[b,:,hh*4:(hh+1)*4,:] in its L2. Each K-row gather is ONE
// contiguous 1KB segment (uniform base + lane*16B): lane = h'*16+t covers
// 4 heads x 16 float4. index_sample is shared across (b,h) so one shuffle-held
// idx vector serves all 4 heads.
__global__ __launch_bounds__(256) void k_sample_scores(
    const float* __restrict__ Q, const float* __restrict__ K,
    const int* __restrict__ idxs, float* __restrict__ M)
{
  int blk = blockIdx.x;
  int g = blk & 7;               // XCD-pinned group
  int chunk = blk >> 3;          // 0..L/4-1
  int b = g >> 1, hh = g & 1;
  int tid = threadIdx.x;
  int w = tid >> 6, lane = tid & 63;
  int t = lane & 15;             // float4 slot within head
  int l = chunk * 4 + w;         // this wave's query

  // q: lane holds float4 #t of head hh*4 + (lane>>4)
  const float4* qp = (const float4*)(Q + ((size_t)(b * L_ + l) * H_ + hh * 4) * D_);
  float4 qv = qp[lane];

  // all 45 sample indices for query l, one per lane
  int s = lane < S_ ? lane : S_ - 1;
  int idxall = idxs[l * S_ + s];

  float vmax = -FLT_MAX, vsum = 0.f;
  for (int c = 0; c < 9; ++c) {          // 9 chunks x 5 rows = 45
    int kidx[5];
    #pragma unroll
    for (int j = 0; j < 5; ++j) kidx[j] = __shfl(idxall, c * 5 + j, 64);
    float4 kv[5];
    #pragma unroll
    for (int j = 0; j < 5; ++j) {
      const float4* kp =
          (const float4*)(K + ((size_t)(b * L_ + kidx[j]) * H_ + hh * 4) * D_);
      kv[j] = kp[lane];
    }
    #pragma unroll
    for (int j = 0; j < 5; ++j) {
      float p = qv.x * kv[j].x;
      p = fmaf(qv.y, kv[j].y, p);
      p = fmaf(qv.z, kv[j].z, p);
      p = fmaf(qv.w, kv[j].w, p);
      p += __shfl_xor(p, 1, 64);
      p += __shfl_xor(p, 2, 64);
      p += __shfl_xor(p, 4, 64);
      p += __shfl_xor(p, 8, 64);   // all 16 lanes of the head group hold the dot
      vmax = fmaxf(vmax, p);
      vsum += p;
    }
  }
  if (t == 0) {
    int h = hh * 4 + (lane >> 4);
    M[(size_t)(b * H_ + h) * L_ + l] = vmax - vsum * (1.0f / L_);
  }
}

// ---------------- K2: top-45 per (b,h), register-resident selection -----------
__device__ __forceinline__ unsigned ordf(float f) {
  unsigned u = __float_as_uint(f);
  return (u & 0x80000000u) ? ~u : (u | 0x80000000u);
}

__global__ __launch_bounds__(256) void k_topk(
    const float* __restrict__ M, int* __restrict__ mtop)
{
  __shared__ unsigned long long cand[4][S_];
  int bh = blockIdx.x;
  int tid = threadIdx.x, w = tid >> 6, lane = tid & 63;
  const float* Mp = M + (size_t)bh * L_;
  unsigned long long key[16];
  #pragma unroll
  for (int j = 0; j < 16; ++j) {
    int gi = w * 1024 + j * 64 + lane;
    key[j] = ((unsigned long long)ordf(Mp[gi]) << 32) | (unsigned)(~gi);
  }
  for (int it = 0; it < S_; ++it) {
    unsigned long long loc = key[0];
    #pragma unroll
    for (int j = 1; j < 16; ++j) loc = key[j] > loc ? key[j] : loc;
    unsigned long long best = loc;
    #pragma unroll
    for (int m = 32; m >= 1; m >>= 1) {
      unsigned long long o = __shfl_xor(best, m, 64);
      best = o > best ? o : best;
    }
    if (loc == best) {
      #pragma unroll
      for (int j = 0; j < 16; ++j) if (key[j] == best) key[j] = 0ull;
    }
    if (lane == 0) cand[w][it] = best;
  }
  __syncthreads();
  if (w == 0) {
    unsigned long long k2[3];
    #pragma unroll
    for (int j = 0; j < 3; ++j) {
      int c = j * 64 + lane;
      k2[j] = (c < 4 * S_) ? cand[c / S_][c % S_] : 0ull;
    }
    for (int it = 0; it < S_; ++it) {
      unsigned long long loc = k2[0];
      loc = k2[1] > loc ? k2[1] : loc;
      loc = k2[2] > loc ? k2[2] : loc;
      unsigned long long best = loc;
      #pragma unroll
      for (int m = 32; m >= 1; m >>= 1) {
        unsigned long long o = __shfl_xor(best, m, 64);
        best = o > best ? o : best;
      }
      if (loc == best) {
        #pragma unroll
        for (int j = 0; j < 3; ++j) if (k2[j] == best) k2[j] = 0ull;
      }
      if (lane == 0) mtop[bh * S_ + it] = (int)(~(unsigned)(best & 0xFFFFFFFFu));
    }
  }
}

// ---------------- K3: per-chunk column sums of V (chunk = 64 rows) ------------
__global__ __launch_bounds__(256) void k_csum_chunks(
    const float* __restrict__ V, float* __restrict__ cs)
{
  int blk = blockIdx.x;          // B*H*16
  int bh = blk >> 4;
  int cg = blk & 15;
  int b = bh >> 3, h = bh & 7;
  int w = threadIdx.x >> 6, d = threadIdx.x & 63;
  int c = cg * 4 + w;
  const float* vp = V + ((size_t)(b * L_ + c * 64) * H_ + h) * D_ + d;
  float sum = 0.f;
  for (int i = 0; i < 64; ++i) sum += vp[(size_t)i * (H_ * D_)];
  cs[((size_t)bh * 64 + c) * D_ + d] = sum;
}

// ---------------- K4: exclusive scan of chunk sums over c ---------------------
__global__ __launch_bounds__(256) void k_csum_scan(float* __restrict__ cs)
{
  int g = blockIdx.x * 256 + threadIdx.x;   // 2048 threads total
  int bh = g >> 6, d = g & 63;
  float run = 0.f;
  for (int c = 0; c < 64; ++c) {
    size_t off = ((size_t)bh * 64 + c) * D_ + d;
    float a = cs[off];
    cs[off] = run;
    run += a;
  }
}

// ---------------- K5: final cumsum write --------------------------------------
__global__ __launch_bounds__(256) void k_csum_write(
    const float* __restrict__ V, const float* __restrict__ cs,
    float* __restrict__ out)
{
  int blk = blockIdx.x;
  int bh = blk >> 4, cg = blk & 15;
  int b = bh >> 3, h = bh & 7;
  int w = threadIdx.x >> 6, d = threadIdx.x & 63;
  int c = cg * 4 + w;
  int l0 = c * 64;
  const float* vp = V + ((size_t)(b * L_ + l0) * H_ + h) * D_ + d;
  float run = cs[((size_t)bh * 64 + c) * D_ + d];
  float* op = out + ((size_t)bh * L_ + l0) * D_ + d;
  for (int i = 0; i < 64; ++i) {
    run += vp[(size_t)i * (H_ * D_)];
    op[(size_t)i * D_] = run;
  }
}

// ---------------- K6: attention partials (unnormalized) -----------------------
__global__ __launch_bounds__(256) void k_attn_partial(
    const float* __restrict__ Q, const float* __restrict__ K,
    const float* __restrict__ V, const int* __restrict__ mtop,
    float* __restrict__ lpart, float* __restrict__ updp)
{
  __shared__ float qr[S_ * D_];      // 11.25 KB
  __shared__ float el[S_ * KCH_];    // 45 KB  (reused as cross-wave scratch)
  __shared__ float lred[4 * S_];
  __shared__ int   cut[S_];
  int blk = blockIdx.x;
  int bh = blk >> 4;                 // / KC_
  int kc = blk & 15;
  int b = bh >> 3, h = bh & 7;
  int tid = threadIdx.x;
  if (tid < S_) cut[tid] = mtop[bh * S_ + tid];
  __syncthreads();
  for (int i = tid; i < S_ * D_; i += 256) {
    int r = i >> 6, d = i & 63;
    qr[i] = Q[((size_t)(b * L_ + cut[r]) * H_ + h) * D_ + d];
  }
  __syncthreads();

  // phase A: scores -> e
  int k = kc * KCH_ + tid;
  float acc[S_];
  #pragma unroll
  for (int r = 0; r < S_; ++r) acc[r] = 0.f;
  const float4* krow = (const float4*)K + ((size_t)(b * L_ + k) * H_ + h) * (D_ / 4);
  const float4* qr4 = (const float4*)qr;
  for (int d4 = 0; d4 < D_ / 4; ++d4) {
    float4 kv = krow[d4];
    #pragma unroll
    for (int r = 0; r < S_; ++r) {
      float4 qv = qr4[r * (D_ / 4) + d4];
      acc[r] = fmaf(qv.x, kv.x, acc[r]);
      acc[r] = fmaf(qv.y, kv.y, acc[r]);
      acc[r] = fmaf(qv.z, kv.z, acc[r]);
      acc[r] = fmaf(qv.w, kv.w, acc[r]);
    }
  }
  #pragma unroll
  for (int r = 0; r < S_; ++r) {
    float e = (k <= cut[r]) ? __expf(acc[r] * SCALE) : 0.f;
    el[r * KCH_ + tid] = e;
    acc[r] = e;
  }
  // partial softmax denominators
  int w = tid >> 6, lane = tid & 63;
  #pragma unroll
  for (int r = 0; r < S_; ++r) {
    float v = acc[r];
    #pragma unroll
    for (int m = 32; m >= 1; m >>= 1) v += __shfl_xor(v, m, 64);
    if (lane == 0) lred[w * S_ + r] = v;
  }
  __syncthreads();
  if (tid < S_)
    lpart[(size_t)blk * S_ + tid] =
        lred[tid] + lred[S_ + tid] + lred[2 * S_ + tid] + lred[3 * S_ + tid];

  // phase B: partial update = e @ V over this chunk
  float acc2[S_];
  #pragma unroll
  for (int r = 0; r < S_; ++r) acc2[r] = 0.f;
  int d = lane;
  const float* vp = V + ((size_t)(b * L_ + kc * KCH_) * H_ + h) * D_ + d;
  for (int kk = 0; kk < 16; ++kk) {
    int kb = w * 64 + kk * 4;
    float v0 = vp[(size_t)(kb + 0) * (H_ * D_)];
    float v1 = vp[(size_t)(kb + 1) * (H_ * D_)];
    float v2 = vp[(size_t)(kb + 2) * (H_ * D_)];
    float v3 = vp[(size_t)(kb + 3) * (H_ * D_)];
    #pragma unroll
    for (int r = 0; r < S_; ++r) {
      float4 e4 = *(const float4*)&el[r * KCH_ + kb];
      acc2[r] = fmaf(e4.x, v0, acc2[r]);
      acc2[r] = fmaf(e4.y, v1, acc2[r]);
      acc2[r] = fmaf(e4.z, v2, acc2[r]);
      acc2[r] = fmaf(e4.w, v3, acc2[r]);
    }
  }
  __syncthreads();   // all reads of el done
  #pragma unroll
  for (int r = 0; r < S_; ++r) el[w * (S_ * D_) + r * D_ + d] = acc2[r];
  __syncthreads();
  for (int i = tid; i < S_ * D_; i += 256) {
    float s = el[i] + el[S_ * D_ + i] + el[2 * S_ * D_ + i] + el[3 * S_ * D_ + i];
    updp[(size_t)blk * (S_ * D_) + i] = s;
  }
}

// ---------------- K7: reduce partials, normalize, scatter over cumsum ---------
__global__ __launch_bounds__(256) void k_finalize(
    const float* __restrict__ lpart, const float* __restrict__ updp,
    const int* __restrict__ mtop, float* __restrict__ out)
{
  __shared__ float linv[S_];
  __shared__ int   mt[S_];
  int bh = blockIdx.x;
  int tid = threadIdx.x;
  if (tid < S_) {
    float l = 0.f;
    for (int kc = 0; kc < KC_; ++kc) l += lpart[(size_t)(bh * KC_ + kc) * S_ + tid];
    linv[tid] = 1.0f / l;
    mt[tid] = mtop[bh * S_ + tid];
  }
  __syncthreads();
  for (int i = tid; i < S_ * D_; i += 256) {
    int r = i >> 6, d = i & 63;
    float u = 0.f;
    for (int kc = 0; kc < KC_; ++kc) u += updp[((size_t)(bh * KC_ + kc)) * (S_ * D_) + i];
    out[((size_t)bh * L_ + mt[r]) * D_ + d] = u * linv[r];
  }
}

extern "C" void kernel_launch(void* const* d_in, const int* in_sizes, int n_in,
                              void* d_out, int out_size, void* d_ws, size_t ws_size,
                              hipStream_t stream) {
  const float* Q = (const float*)d_in[0];
  const float* K = (const float*)d_in[1];
  const float* V = (const float*)d_in[2];
  const int*   I = (const int*)d_in[3];
  float* out = (float*)d_out;
  float* ws = (float*)d_ws;

  float* M     = ws;                       // 131072 floats
  float* cs    = ws + 131072;              // 131072 floats
  float* lpart = ws + 262144;              // 32*16*45 = 23040 floats
  float* updp  = ws + 262144 + 23040;      // 32*16*45*64 = 1474560 floats
  int*   mtop  = (int*)(ws + 262144 + 23040 + 1474560);   // 1440 ints

  k_sample_scores<<<(L_ / 4) * 8, 256, 0, stream>>>(Q, K, I, M);
  k_topk<<<B_ * H_, 256, 0, stream>>>(M, mtop);
  k_csum_chunks<<<B_ * H_ * 16, 256, 0, stream>>>(V, cs);
  k_csum_scan<<<8, 256, 0, stream>>>(cs);
  k_csum_write<<<B_ * H_ * 16, 256, 0, stream>>>(V, cs, out);
  k_attn_partial<<<B_ * H_ * KC_, 256, 0, stream>>>(Q, K, V, mtop, lpart, updp);
  k_finalize<<<B_ * H_, 256, 0, stream>>>(lpart, updp, mtop, out);
}